// Round 5
// baseline (445.862 us; speedup 1.0000x reference)
//
#include <hip/hip_runtime.h>

typedef __bf16 bf16x8 __attribute__((ext_vector_type(8)));
typedef float f32x4 __attribute__((ext_vector_type(4)));

// ---- workspace layout (bf16 element offsets) ----
#define W0T_OFF 0                   // [512][32]  (k padded 16->32 with zeros)
#define W1T_OFF 16384               // [512][512]
#define W2T_OFF (16384 + 262144)    // [144][512] (n padded 136->144 with zeros)
#define PREP_TOTAL (16384 + 262144 + 73728)

__global__ void prep_weights(const float* __restrict__ W0,
                             const float* __restrict__ W1,
                             const float* __restrict__ W2,
                             __bf16* __restrict__ ws) {
    int t = blockIdx.x * 256 + threadIdx.x;
    if (t < 16384) {
        int n = t >> 5, k = t & 31;
        ws[W0T_OFF + t] = (k < 16) ? (__bf16)W0[k * 512 + n] : (__bf16)0.0f;
    } else if (t < 16384 + 262144) {
        int u = t - 16384;
        int n = u >> 9, k = u & 511;
        ws[W1T_OFF + u] = (__bf16)W1[k * 512 + n];
    } else if (t < PREP_TOTAL) {
        int u = t - (16384 + 262144);
        int n = u >> 9, k = u & 511;
        ws[W2T_OFF + u] = (n < 136) ? (__bf16)W2[k * 136 + n] : (__bf16)0.0f;
    }
}

__device__ __forceinline__ float fast_tanh(float x) {
    // tanh(x) = 1 - 2/(exp2(2*log2e*x)+1); exp2->inf/0 gives correct +-1 saturation
#if __has_builtin(__builtin_amdgcn_exp2f)
    float e = __builtin_amdgcn_exp2f(x * 2.885390081777926f);
#else
    float e = exp2f(x * 2.885390081777926f);
#endif
    return 1.0f - 2.0f * __builtin_amdgcn_rcpf(e + 1.0f);
}

// h LDS layout: [64][512] bf16; 16B k-blocks XOR-swizzled by
// s(m) = ((m>>2)&3)<<1 ^ (m&7). Writes: the 4 quads (m = q*4+r) map to 4
// DISJOINT bank groups (2 lanes/bank = free); reads: 2-way-equivalent (free).
__device__ __forceinline__ int h_swz(int m) {
    return (((m >> 2) & 3) << 1) ^ (m & 7);
}
__device__ __forceinline__ int h_idx(int m, int k) {
    return m * 512 + (((k >> 3) ^ h_swz(m)) << 3) + (k & 7);
}

// 256 threads (4 waves), BM=64. Per-wave phase-1 tile 64x128:
// acc[8][4]=128 regs (AGPR side of the unified file) + small arch set.
// NOTE: NO lookahead pragmas/arrays in the K-loops. R1/R2/R4 A/B showed any
// 2-iter lookahead (arrays OR #pragma unroll 2) on top of the 128-reg acc
// overflows the arch-VGPR share -> ~100 MB scratch spill. Plain loop = 0 spill.
__global__ __launch_bounds__(256, 2)
void fused_mlp_quad(const float* __restrict__ points,
                    const float* __restrict__ b0,
                    const float* __restrict__ b1,
                    const float* __restrict__ b2,
                    const __bf16* __restrict__ ws,
                    float* __restrict__ out) {
    __shared__ __align__(16) unsigned char lds_raw[65536];
    __bf16* h  = (__bf16*)lds_raw;   // [64][512] swizzled bf16 (h0, then h1 in place)
    float* net = (float*)lds_raw;    // [64][137] fp32, overlays h after phase 2

    const __bf16* w0t = ws + W0T_OFF;
    const __bf16* w1t = ws + W1T_OFF;
    const __bf16* w2t = ws + W2T_OFF;

    const int tid = threadIdx.x;
    const int w   = tid >> 6;    // wave 0..3
    const int l   = tid & 63;
    const int c   = l & 15;      // MFMA lane col
    const int q   = l >> 4;      // quad
    const int row0 = blockIdx.x * 64;

    // ---------- phase 0: h0 = tanh(x @ W0 + b0) ----------
    {
        bf16x8 ax[4];
#pragma unroll
        for (int mt = 0; mt < 4; ++mt) {
            bf16x8 a;
#pragma unroll
            for (int j = 0; j < 8; ++j) a[j] = (__bf16)0.0f;
            if (q < 2) {
                const float* src = points + (row0 + mt * 16 + c) * 16 + q * 8;
                float4 p0 = ((const float4*)src)[0];
                float4 p1 = ((const float4*)src)[1];
                a[0] = (__bf16)p0.x; a[1] = (__bf16)p0.y;
                a[2] = (__bf16)p0.z; a[3] = (__bf16)p0.w;
                a[4] = (__bf16)p1.x; a[5] = (__bf16)p1.y;
                a[6] = (__bf16)p1.z; a[7] = (__bf16)p1.w;
            }
            ax[mt] = a;
        }
#pragma unroll
        for (int t = 0; t < 8; ++t) {
            const int n = (w * 8 + t) * 16 + c;
            bf16x8 b = *(const bf16x8*)(w0t + n * 32 + q * 8);
            float bias = b0[n];
#pragma unroll
            for (int mt = 0; mt < 4; ++mt) {
                f32x4 acc = {0.f, 0.f, 0.f, 0.f};
                acc = __builtin_amdgcn_mfma_f32_16x16x32_bf16(ax[mt], b, acc, 0, 0, 0);
#pragma unroll
                for (int r = 0; r < 4; ++r) {
                    int m = mt * 16 + q * 4 + r;
                    h[h_idx(m, n)] = (__bf16)fast_tanh(acc[r] + bias);
                }
            }
        }
    }
    __syncthreads();

    // ---------- phase 1: h1 = tanh(h0 @ W1 + b1), acc in regs, h1 in place ----------
    // wave w: n-cols [w*128, w*128+128) -> 8 n-tiles x 4 m-tiles, acc = 128 regs
    f32x4 acc1[8][4] = {};
    {
        const __bf16* abase[4];
        int asw[4];
#pragma unroll
        for (int mt = 0; mt < 4; ++mt) {
            int m = mt * 16 + c;
            abase[mt] = h + m * 512;
            asw[mt] = h_swz(m);
        }
        const __bf16* bbase = w1t + (w * 128 + c) * 512 + q * 8;  // + t*8192 + kk*32
        for (int kk = 0; kk < 16; ++kk) {
            const int blk = (kk << 2) + q;
            bf16x8 a[4];
#pragma unroll
            for (int mt = 0; mt < 4; ++mt)
                a[mt] = *(const bf16x8*)(abase[mt] + ((blk ^ asw[mt]) << 3));
#pragma unroll
            for (int t = 0; t < 8; ++t) {
                bf16x8 b = *(const bf16x8*)(bbase + t * 8192 + kk * 32);
#pragma unroll
                for (int mt = 0; mt < 4; ++mt)
                    acc1[t][mt] = __builtin_amdgcn_mfma_f32_16x16x32_bf16(
                        a[mt], b, acc1[t][mt], 0, 0, 0);
            }
        }
    }
    __syncthreads();   // all reads of h0 done; safe to overwrite
#pragma unroll
    for (int t = 0; t < 8; ++t) {
        const int n = (w * 8 + t) * 16 + c;
        float bias = b1[n];
#pragma unroll
        for (int mt = 0; mt < 4; ++mt) {
#pragma unroll
            for (int r = 0; r < 4; ++r) {
                int m = mt * 16 + q * 4 + r;
                h[h_idx(m, n)] = (__bf16)fast_tanh(acc1[t][mt][r] + bias);
            }
        }
    }
    __syncthreads();

    // ---------- phase 2: net = h1 @ W2 + b2  (N padded to 144 -> 9 n-tiles) ----------
    // 36 (nt,mt) tiles over 4 waves = 9/wave: (w,0..3), (w+4,0..3), (8,w)
    f32x4 acc2[9] = {};
    {
        const __bf16* abase[4];
        int asw[4];
#pragma unroll
        for (int mt = 0; mt < 4; ++mt) {
            int m = mt * 16 + c;
            abase[mt] = h + m * 512;
            asw[mt] = h_swz(m);
        }
        for (int kk = 0; kk < 16; ++kk) {
            const int blk = (kk << 2) + q;
            bf16x8 a[4];
#pragma unroll
            for (int mt = 0; mt < 4; ++mt)
                a[mt] = *(const bf16x8*)(abase[mt] + ((blk ^ asw[mt]) << 3));
            // group j=0: tiles (w, mt=0..3); j=1: (w+4, mt=0..3); j=2: (8, mt=w)
            {
                bf16x8 b = *(const bf16x8*)(w2t + (w * 16 + c) * 512 + kk * 32 + q * 8);
#pragma unroll
                for (int i = 0; i < 4; ++i)
                    acc2[i] = __builtin_amdgcn_mfma_f32_16x16x32_bf16(a[i], b, acc2[i], 0, 0, 0);
            }
            {
                bf16x8 b = *(const bf16x8*)(w2t + ((w + 4) * 16 + c) * 512 + kk * 32 + q * 8);
#pragma unroll
                for (int i = 0; i < 4; ++i)
                    acc2[4 + i] = __builtin_amdgcn_mfma_f32_16x16x32_bf16(a[i], b, acc2[4 + i], 0, 0, 0);
            }
            {
                bf16x8 b = *(const bf16x8*)(w2t + (8 * 16 + c) * 512 + kk * 32 + q * 8);
                acc2[8] = __builtin_amdgcn_mfma_f32_16x16x32_bf16(a[w], b, acc2[8], 0, 0, 0);
            }
        }
    }
    __syncthreads();   // all reads of h1 done; overwrite with net (fp32)
#pragma unroll
    for (int i = 0; i < 9; ++i) {
        const int ntl = (i < 4) ? w : (i < 8) ? (w + 4) : 8;
        const int mt  = (i < 8) ? (i & 3) : w;
        const int n = ntl * 16 + c;
        if (n < 136) {
            float bias = b2[n];
#pragma unroll
            for (int r = 0; r < 4; ++r) {
                int m = mt * 16 + q * 4 + r;
                net[m * 137 + n] = acc2[i][r] + bias;
            }
        }
    }
    __syncthreads();

    // ---------- phase 3: vals = ||M^T x||^2 + eps*||x||^2 ----------
    // 8 threads per row; 32 rows per pass, 2 passes
#pragma unroll
    for (int half = 0; half < 2; ++half) {
        const int r  = half * 32 + (tid >> 3);
        const int jg = tid & 7;
        const float* xp = points + (row0 + r) * 16;
        float xv[16];
#pragma unroll
        for (int i = 0; i < 4; ++i) {
            float4 v = ((const float4*)xp)[i];
            xv[i * 4 + 0] = v.x; xv[i * 4 + 1] = v.y;
            xv[i * 4 + 2] = v.z; xv[i * 4 + 3] = v.w;
        }
        float sumsq = 0.f;
#pragma unroll
        for (int i = 0; i < 16; ++i) sumsq += xv[i] * xv[i];
        float p = 0.f;
#pragma unroll
        for (int jj = 0; jj < 2; ++jj) {
            const int j = jg + jj * 8;
            float y = 0.f;
#pragma unroll
            for (int i = 0; i < 16; ++i) {
                float mv = net[r * 137 + ((i * (i + 1)) >> 1) + j];
                y += (i >= j) ? mv * xv[i] : 0.f;
            }
            p += y * y;
        }
        p += __shfl_xor(p, 1);
        p += __shfl_xor(p, 2);
        p += __shfl_xor(p, 4);
        if (jg == 0) out[row0 + r] = p + 1e-6f * sumsq;
    }
}

extern "C" void kernel_launch(void* const* d_in, const int* in_sizes, int n_in,
                              void* d_out, int out_size, void* d_ws, size_t ws_size,
                              hipStream_t stream) {
    const float* points = (const float*)d_in[0];
    const float* W0 = (const float*)d_in[1];
    const float* b0 = (const float*)d_in[2];
    const float* W1 = (const float*)d_in[3];
    const float* b1 = (const float*)d_in[4];
    const float* W2 = (const float*)d_in[5];
    const float* b2 = (const float*)d_in[6];
    __bf16* ws = (__bf16*)d_ws;
    float* out = (float*)d_out;

    prep_weights<<<(PREP_TOTAL + 255) / 256, 256, 0, stream>>>(W0, W1, W2, ws);

    const int B = in_sizes[0] / 16;   // 131072
    fused_mlp_quad<<<B / 64, 256, 0, stream>>>(points, b0, b1, b2, ws, out);
}

// Round 6
// 443.863 us; speedup vs baseline: 1.0045x; 1.0045x over previous
//
#include <hip/hip_runtime.h>

typedef __bf16 bf16x8 __attribute__((ext_vector_type(8)));
typedef float f32x16 __attribute__((ext_vector_type(16)));

// ---- workspace layout (bf16 element offsets) ----
#define W0T_OFF 0                 // [512][16]  (K=16, no padding: one 32x32x16 step)
#define W1T_OFF 8192              // [512][512]
#define W2T_OFF (8192 + 262144)   // [160][512] (n padded 136->160 with zeros)
#define PREP_TOTAL (8192 + 262144 + 81920)

__global__ void prep_weights(const float* __restrict__ W0,
                             const float* __restrict__ W1,
                             const float* __restrict__ W2,
                             __bf16* __restrict__ ws) {
    int t = blockIdx.x * 256 + threadIdx.x;
    if (t < 8192) {
        int n = t >> 4, k = t & 15;
        ws[W0T_OFF + t] = (__bf16)W0[k * 512 + n];
    } else if (t < 8192 + 262144) {
        int u = t - 8192;
        int n = u >> 9, k = u & 511;
        ws[W1T_OFF + u] = (__bf16)W1[k * 512 + n];
    } else if (t < PREP_TOTAL) {
        int u = t - (8192 + 262144);
        int n = u >> 9, k = u & 511;
        ws[W2T_OFF + u] = (n < 136) ? (__bf16)W2[k * 136 + n] : (__bf16)0.0f;
    }
}

__device__ __forceinline__ float fast_tanh(float x) {
#if __has_builtin(__builtin_amdgcn_exp2f)
    float e = __builtin_amdgcn_exp2f(x * 2.885390081777926f);
#else
    float e = exp2f(x * 2.885390081777926f);
#endif
    return 1.0f - 2.0f * __builtin_amdgcn_rcpf(e + 1.0f);
}

// h LDS: [64][512] bf16, 16B k-blocks XOR-swizzled by (m&7).
// 32x32x16 A-read: 32 lanes (rows m..m+31, same k-block) spread across all 8
// chunk groups -> b128 floor (8 words/bank). Writes: scalar b16, <=2-way.
__device__ __forceinline__ int h_idx(int m, int k) {
    return m * 512 + ((((k >> 3) ^ (m & 7)) << 3)) + (k & 7);
}

// 32x32x16_bf16 fragment maps (C/D verified m74/m101; A/B standard K-contig):
//   A: m = lane&31, k = (lane>>5)*8 + j   (8 bf16 = 4 VGPRs)
//   B: n = lane&31, k = (lane>>5)*8 + j
//   C/D: col = lane&31, row = (reg&3) + 8*(reg>>2) + 4*(lane>>5)
__global__ __launch_bounds__(512, 4)
void fused_mlp_quad(const float* __restrict__ points,
                    const float* __restrict__ b0,
                    const float* __restrict__ b1,
                    const float* __restrict__ b2,
                    const __bf16* __restrict__ ws,
                    float* __restrict__ out) {
    __shared__ __align__(16) unsigned char lds_raw[65536];
    __bf16* h  = (__bf16*)lds_raw;   // [64][512] swizzled bf16 (h0, then h1 in place)
    float* net = (float*)lds_raw;    // [64][137] fp32 overlay after phase 2

    const __bf16* w0t = ws + W0T_OFF;
    const __bf16* w1t = ws + W1T_OFF;
    const __bf16* w2t = ws + W2T_OFF;

    const int tid = threadIdx.x;
    const int w   = tid >> 6;     // wave 0..7
    const int l   = tid & 63;
    const int ln  = l & 31;       // 32x32 lane col/row index
    const int hi  = l >> 5;       // k-half
    const int row0 = blockIdx.x * 64;

    const int mt  = w >> 2;            // m-tile (rows mt*32..+31)
    const int ncb = (w & 3) * 128;     // n-col base for phases 0/1

    // ---------- phase 0: h0 = tanh(x @ W0 + b0), K=16 = one MFMA ----------
    {
        // A-frag: x[row0 + mt*32 + ln][hi*8 .. +7]
        const float* src = points + (row0 + mt * 32 + ln) * 16 + hi * 8;
        float4 p0 = ((const float4*)src)[0];
        float4 p1 = ((const float4*)src)[1];
        bf16x8 a;
        a[0] = (__bf16)p0.x; a[1] = (__bf16)p0.y; a[2] = (__bf16)p0.z; a[3] = (__bf16)p0.w;
        a[4] = (__bf16)p1.x; a[5] = (__bf16)p1.y; a[6] = (__bf16)p1.z; a[7] = (__bf16)p1.w;
#pragma unroll
        for (int t4 = 0; t4 < 4; ++t4) {
            const int n = ncb + t4 * 32 + ln;
            bf16x8 b = *(const bf16x8*)(w0t + n * 16 + hi * 8);
            float bias = b0[n];
            f32x16 acc = {};
            acc = __builtin_amdgcn_mfma_f32_32x32x16_bf16(a, b, acc, 0, 0, 0);
#pragma unroll
            for (int r = 0; r < 16; ++r) {
                int m = mt * 32 + (r & 3) + 8 * (r >> 2) + 4 * hi;
                h[h_idx(m, n)] = (__bf16)fast_tanh(acc[r] + bias);
            }
        }
    }
    __syncthreads();

    // ---------- phase 1: h1 = tanh(h0 @ W1 + b1) ----------
    // wave tile: 32 rows (mt) x 128 cols (ncb..+127) = 4 n-tiles; acc = 64 regs
    f32x16 acc1[4] = {};
    {
        const int am = mt * 32 + ln;
        const __bf16* arow = h + am * 512;
        const int asw = am & 7;
        for (int kk = 0; kk < 32; ++kk) {
            bf16x8 a = *(const bf16x8*)(arow + ((((kk << 1) + hi) ^ asw) << 3));
#pragma unroll
            for (int t = 0; t < 4; ++t) {
                bf16x8 b = *(const bf16x8*)(w1t + (ncb + t * 32 + ln) * 512 + kk * 16 + hi * 8);
                acc1[t] = __builtin_amdgcn_mfma_f32_32x32x16_bf16(a, b, acc1[t], 0, 0, 0);
            }
        }
    }
    __syncthreads();   // all h0 reads done; overwrite in place
#pragma unroll
    for (int t = 0; t < 4; ++t) {
        const int n = ncb + t * 32 + ln;
        float bias = b1[n];
#pragma unroll
        for (int r = 0; r < 16; ++r) {
            int m = mt * 32 + (r & 3) + 8 * (r >> 2) + 4 * hi;
            h[h_idx(m, n)] = (__bf16)fast_tanh(acc1[t][r] + bias);
        }
    }
    __syncthreads();

    // ---------- phase 2: net = h1 @ W2 + b2  (N padded 160 -> 5 n-tiles x 2 m-tiles) ----------
    // 10 tiles: T=w -> (mt2 = w&1, nt2 = w>>1); waves 0,1 also take T=8,9 -> (mt2, nt=4)
    f32x16 acc2a = {}, acc2b = {};
    const int mt2 = w & 1;
    const int nt2 = w >> 1;
    {
        const int am = mt2 * 32 + ln;
        const __bf16* arow = h + am * 512;
        const int asw = am & 7;
        const bool two = (w < 2);
        for (int kk = 0; kk < 32; ++kk) {
            bf16x8 a = *(const bf16x8*)(arow + ((((kk << 1) + hi) ^ asw) << 3));
            bf16x8 b = *(const bf16x8*)(w2t + (nt2 * 32 + ln) * 512 + kk * 16 + hi * 8);
            acc2a = __builtin_amdgcn_mfma_f32_32x32x16_bf16(a, b, acc2a, 0, 0, 0);
            if (two) {
                bf16x8 b2f = *(const bf16x8*)(w2t + (128 + ln) * 512 + kk * 16 + hi * 8);
                acc2b = __builtin_amdgcn_mfma_f32_32x32x16_bf16(a, b2f, acc2b, 0, 0, 0);
            }
        }
    }
    __syncthreads();   // all h1 reads done; overwrite with net (fp32)
    {
        const int n = nt2 * 32 + ln;
        float bias = b2[n];   // n < 136 always here (nt2<=3 -> n<=127)
#pragma unroll
        for (int r = 0; r < 16; ++r) {
            int m = mt2 * 32 + (r & 3) + 8 * (r >> 2) + 4 * hi;
            net[m * 137 + n] = acc2a[r] + bias;
        }
        if (w < 2) {
            const int n2 = 128 + ln;
            if (n2 < 136) {
                float bias2 = b2[n2];
#pragma unroll
                for (int r = 0; r < 16; ++r) {
                    int m = mt2 * 32 + (r & 3) + 8 * (r >> 2) + 4 * hi;
                    net[m * 137 + n2] = acc2b[r] + bias2;
                }
            }
        }
    }
    __syncthreads();

    // ---------- phase 3: vals = ||M^T x||^2 + eps*||x||^2 ----------
    // 8 threads per row x 64 rows = 512 threads, single pass
    {
        const int r  = tid >> 3;
        const int jg = tid & 7;
        const float* xp = points + (row0 + r) * 16;
        float xv[16];
#pragma unroll
        for (int i = 0; i < 4; ++i) {
            float4 v = ((const float4*)xp)[i];
            xv[i * 4 + 0] = v.x; xv[i * 4 + 1] = v.y;
            xv[i * 4 + 2] = v.z; xv[i * 4 + 3] = v.w;
        }
        float sumsq = 0.f;
#pragma unroll
        for (int i = 0; i < 16; ++i) sumsq += xv[i] * xv[i];
        float p = 0.f;
#pragma unroll
        for (int jj = 0; jj < 2; ++jj) {
            const int j = jg + jj * 8;
            float y = 0.f;
#pragma unroll
            for (int i = 0; i < 16; ++i) {
                float mv = net[r * 137 + ((i * (i + 1)) >> 1) + j];
                y += (i >= j) ? mv * xv[i] : 0.f;
            }
            p += y * y;
        }
        p += __shfl_xor(p, 1);
        p += __shfl_xor(p, 2);
        p += __shfl_xor(p, 4);
        if (jg == 0) out[row0 + r] = p + 1e-6f * sumsq;
    }
}

extern "C" void kernel_launch(void* const* d_in, const int* in_sizes, int n_in,
                              void* d_out, int out_size, void* d_ws, size_t ws_size,
                              hipStream_t stream) {
    const float* points = (const float*)d_in[0];
    const float* W0 = (const float*)d_in[1];
    const float* b0 = (const float*)d_in[2];
    const float* W1 = (const float*)d_in[3];
    const float* b1 = (const float*)d_in[4];
    const float* W2 = (const float*)d_in[5];
    const float* b2 = (const float*)d_in[6];
    __bf16* ws = (__bf16*)d_ws;
    float* out = (float*)d_out;

    prep_weights<<<(PREP_TOTAL + 255) / 256, 256, 0, stream>>>(W0, W1, W2, ws);

    const int B = in_sizes[0] / 16;   // 131072
    fused_mlp_quad<<<B / 64, 512, 0, stream>>>(points, b0, b1, b2, ws, out);
}

// Round 7
// 325.209 us; speedup vs baseline: 1.3710x; 1.3649x over previous
//
#include <hip/hip_runtime.h>

typedef __bf16 bf16x8 __attribute__((ext_vector_type(8)));
typedef float f32x16 __attribute__((ext_vector_type(16)));

// ---- workspace layout (bf16 element offsets) ----
#define W0T_OFF 0                 // [512][16]  (K=16: one 32x32x16 step)
#define W1T_OFF 8192              // [512][512]
#define W2T_OFF (8192 + 262144)   // [160][512] (n padded 136->160 with zeros)
#define PREP_TOTAL (8192 + 262144 + 81920)

__global__ void prep_weights(const float* __restrict__ W0,
                             const float* __restrict__ W1,
                             const float* __restrict__ W2,
                             __bf16* __restrict__ ws) {
    int t = blockIdx.x * 256 + threadIdx.x;
    if (t < 8192) {
        int n = t >> 4, k = t & 15;
        ws[W0T_OFF + t] = (__bf16)W0[k * 512 + n];
    } else if (t < 8192 + 262144) {
        int u = t - 8192;
        int n = u >> 9, k = u & 511;
        ws[W1T_OFF + u] = (__bf16)W1[k * 512 + n];
    } else if (t < PREP_TOTAL) {
        int u = t - (8192 + 262144);
        int n = u >> 9, k = u & 511;
        ws[W2T_OFF + u] = (n < 136) ? (__bf16)W2[k * 136 + n] : (__bf16)0.0f;
    }
}

__device__ __forceinline__ float fast_tanh(float x) {
#if __has_builtin(__builtin_amdgcn_exp2f)
    float e = __builtin_amdgcn_exp2f(x * 2.885390081777926f);
#else
    float e = exp2f(x * 2.885390081777926f);
#endif
    return 1.0f - 2.0f * __builtin_amdgcn_rcpf(e + 1.0f);
}

// h LDS: [64][512] bf16, 16B k-blocks XOR-swizzled by (m&7).
__device__ __forceinline__ int h_idx(int m, int k) {
    return m * 512 + ((((k >> 3) ^ (m & 7)) << 3)) + (k & 7);
}

// 32x32x16_bf16 fragment maps (C/D verified m74/m101; A/B K-contig):
//   A/B: m|n = lane&31, k = (lane>>5)*8 + j
//   C/D: col = lane&31, row = (reg&3) + 8*(reg>>2) + 4*(lane>>5)
//
// Occupancy note (R2-R6 lesson): ANY launch-bounds cap below natural register
// demand causes 100-240 MB scratch spill -> ~400 us floor. (512,2) leaves the
// allocator free (cap 256); natural demand ~130-160 -> 3 waves/EU, 0 spill.
__global__ __launch_bounds__(512, 2)
void fused_mlp_quad(const float* __restrict__ points,
                    const float* __restrict__ b0,
                    const float* __restrict__ b1,
                    const float* __restrict__ b2,
                    const __bf16* __restrict__ ws,
                    float* __restrict__ out) {
    __shared__ __align__(16) unsigned char lds_raw[65536];
    __bf16* h  = (__bf16*)lds_raw;   // [64][512] swizzled bf16 (h0, then h1 in place)
    float* net = (float*)lds_raw;    // [64][137] fp32 overlay after phase 2

    const __bf16* w0t = ws + W0T_OFF;
    const __bf16* w1t = ws + W1T_OFF;
    const __bf16* w2t = ws + W2T_OFF;

    const int tid = threadIdx.x;
    const int w   = tid >> 6;     // wave 0..7
    const int l   = tid & 63;
    const int ln  = l & 31;       // 32x32 lane index
    const int hi  = l >> 5;       // k-half
    const int row0 = blockIdx.x * 64;

    const int ncb = w * 64;       // wave owns cols [ncb, ncb+64) for BOTH m-tiles

    // ---------- phase 0: h0 = tanh(x @ W0 + b0), K=16 = one MFMA step ----------
    {
        bf16x8 a[2];
#pragma unroll
        for (int mt = 0; mt < 2; ++mt) {
            const float* src = points + (row0 + mt * 32 + ln) * 16 + hi * 8;
            float4 p0 = ((const float4*)src)[0];
            float4 p1 = ((const float4*)src)[1];
            bf16x8 t;
            t[0] = (__bf16)p0.x; t[1] = (__bf16)p0.y; t[2] = (__bf16)p0.z; t[3] = (__bf16)p0.w;
            t[4] = (__bf16)p1.x; t[5] = (__bf16)p1.y; t[6] = (__bf16)p1.z; t[7] = (__bf16)p1.w;
            a[mt] = t;
        }
#pragma unroll
        for (int nt = 0; nt < 2; ++nt) {
            const int n = ncb + nt * 32 + ln;
            bf16x8 b = *(const bf16x8*)(w0t + n * 16 + hi * 8);
            float bias = b0[n];
#pragma unroll
            for (int mt = 0; mt < 2; ++mt) {
                f32x16 acc = {};
                acc = __builtin_amdgcn_mfma_f32_32x32x16_bf16(a[mt], b, acc, 0, 0, 0);
#pragma unroll
                for (int r = 0; r < 16; ++r) {
                    int m = mt * 32 + (r & 3) + 8 * (r >> 2) + 4 * hi;
                    h[h_idx(m, n)] = (__bf16)fast_tanh(acc[r] + bias);
                }
            }
        }
    }
    __syncthreads();

    // ---------- phase 1: h1 = tanh(h0 @ W1 + b1) ----------
    // wave tile: 64 rows x 64 cols = 2 m-tiles x 2 n-tiles; acc = 64 AGPR.
    // Each b-frag feeds 2 MFMAs; W1 read exactly once per block (512 KB L2).
    f32x16 acc1[2][2] = {};
    {
        const __bf16* arow0 = h + ln * 512;          // m-tile 0, row ln
        const __bf16* arow1 = h + (32 + ln) * 512;   // m-tile 1, row 32+ln
        const int asw = ln & 7;                      // (32+ln)&7 == ln&7
        for (int kk = 0; kk < 32; ++kk) {
            const int koff = ((((kk << 1) + hi) ^ asw) << 3);
            bf16x8 a0 = *(const bf16x8*)(arow0 + koff);
            bf16x8 a1 = *(const bf16x8*)(arow1 + koff);
#pragma unroll
            for (int nt = 0; nt < 2; ++nt) {
                bf16x8 b = *(const bf16x8*)(w1t + (ncb + nt * 32 + ln) * 512 + kk * 16 + hi * 8);
                acc1[0][nt] = __builtin_amdgcn_mfma_f32_32x32x16_bf16(a0, b, acc1[0][nt], 0, 0, 0);
                acc1[1][nt] = __builtin_amdgcn_mfma_f32_32x32x16_bf16(a1, b, acc1[1][nt], 0, 0, 0);
            }
        }
    }
    __syncthreads();   // all h0 reads done; overwrite in place
#pragma unroll
    for (int nt = 0; nt < 2; ++nt) {
        const int n = ncb + nt * 32 + ln;
        float bias = b1[n];
#pragma unroll
        for (int mt = 0; mt < 2; ++mt) {
#pragma unroll
            for (int r = 0; r < 16; ++r) {
                int m = mt * 32 + (r & 3) + 8 * (r >> 2) + 4 * hi;
                h[h_idx(m, n)] = (__bf16)fast_tanh(acc1[mt][nt][r] + bias);
            }
        }
    }
    __syncthreads();

    // ---------- phase 2: net = h1 @ W2 + b2  (N padded 160 -> 5 nt x 2 mt) ----------
    // tile T: mt2 = T&1, nt2 = T>>1; T=w for all waves, plus T=8,9 on waves 0,1
    f32x16 acc2a = {}, acc2b = {};
    const int mt2 = w & 1;
    const int nt2 = w >> 1;
    {
        const __bf16* arow = h + (mt2 * 32 + ln) * 512;
        const int asw = ln & 7;
        const bool two = (w < 2);
        for (int kk = 0; kk < 32; ++kk) {
            bf16x8 a = *(const bf16x8*)(arow + ((((kk << 1) + hi) ^ asw) << 3));
            bf16x8 b = *(const bf16x8*)(w2t + (nt2 * 32 + ln) * 512 + kk * 16 + hi * 8);
            acc2a = __builtin_amdgcn_mfma_f32_32x32x16_bf16(a, b, acc2a, 0, 0, 0);
            if (two) {
                bf16x8 b2f = *(const bf16x8*)(w2t + (128 + ln) * 512 + kk * 16 + hi * 8);
                acc2b = __builtin_amdgcn_mfma_f32_32x32x16_bf16(a, b2f, acc2b, 0, 0, 0);
            }
        }
    }
    __syncthreads();   // all h1 reads done; overwrite with net (fp32)
    {
        const int n = nt2 * 32 + ln;
        float bias = b2[n];   // nt2<=3 -> n<=127 < 136 always
#pragma unroll
        for (int r = 0; r < 16; ++r) {
            int m = mt2 * 32 + (r & 3) + 8 * (r >> 2) + 4 * hi;
            net[m * 137 + n] = acc2a[r] + bias;
        }
        if (w < 2) {
            const int n2 = 128 + ln;
            if (n2 < 136) {
                float bias2 = b2[n2];
#pragma unroll
                for (int r = 0; r < 16; ++r) {
                    int m = mt2 * 32 + (r & 3) + 8 * (r >> 2) + 4 * hi;
                    net[m * 137 + n2] = acc2b[r] + bias2;
                }
            }
        }
    }
    __syncthreads();

    // ---------- phase 3: vals = ||M^T x||^2 + eps*||x||^2 ----------
    // 8 threads per row x 64 rows = 512 threads, single pass
    {
        const int r  = tid >> 3;
        const int jg = tid & 7;
        const float* xp = points + (row0 + r) * 16;
        float xv[16];
#pragma unroll
        for (int i = 0; i < 4; ++i) {
            float4 v = ((const float4*)xp)[i];
            xv[i * 4 + 0] = v.x; xv[i * 4 + 1] = v.y;
            xv[i * 4 + 2] = v.z; xv[i * 4 + 3] = v.w;
        }
        float sumsq = 0.f;
#pragma unroll
        for (int i = 0; i < 16; ++i) sumsq += xv[i] * xv[i];
        float p = 0.f;
#pragma unroll
        for (int jj = 0; jj < 2; ++jj) {
            const int j = jg + jj * 8;
            float y = 0.f;
#pragma unroll
            for (int i = 0; i < 16; ++i) {
                float mv = net[r * 137 + ((i * (i + 1)) >> 1) + j];
                y += (i >= j) ? mv * xv[i] : 0.f;
            }
            p += y * y;
        }
        p += __shfl_xor(p, 1);
        p += __shfl_xor(p, 2);
        p += __shfl_xor(p, 4);
        if (jg == 0) out[row0 + r] = p + 1e-6f * sumsq;
    }
}

extern "C" void kernel_launch(void* const* d_in, const int* in_sizes, int n_in,
                              void* d_out, int out_size, void* d_ws, size_t ws_size,
                              hipStream_t stream) {
    const float* points = (const float*)d_in[0];
    const float* W0 = (const float*)d_in[1];
    const float* b0 = (const float*)d_in[2];
    const float* W1 = (const float*)d_in[3];
    const float* b1 = (const float*)d_in[4];
    const float* W2 = (const float*)d_in[5];
    const float* b2 = (const float*)d_in[6];
    __bf16* ws = (__bf16*)d_ws;
    float* out = (float*)d_out;

    prep_weights<<<(PREP_TOTAL + 255) / 256, 256, 0, stream>>>(W0, W1, W2, ws);

    const int B = in_sizes[0] / 16;   // 131072
    fused_mlp_quad<<<B / 64, 512, 0, stream>>>(points, b0, b1, b2, ws, out);
}

// Round 8
// 321.934 us; speedup vs baseline: 1.3849x; 1.0102x over previous
//
#include <hip/hip_runtime.h>

typedef __bf16 bf16x8 __attribute__((ext_vector_type(8)));
typedef float f32x16 __attribute__((ext_vector_type(16)));

// ---- workspace layout (bf16 element offsets) ----
#define W0T_OFF 0                 // [512][16]  (K=16: one 32x32x16 step)
#define W1T_OFF 8192              // [512][512]
#define W2T_OFF (8192 + 262144)   // [160][512] (n padded 136->160 with zeros)
#define PREP_TOTAL (8192 + 262144 + 81920)

__global__ void prep_weights(const float* __restrict__ W0,
                             const float* __restrict__ W1,
                             const float* __restrict__ W2,
                             __bf16* __restrict__ ws) {
    int t = blockIdx.x * 256 + threadIdx.x;
    if (t < 8192) {
        int n = t >> 4, k = t & 15;
        ws[W0T_OFF + t] = (__bf16)W0[k * 512 + n];
    } else if (t < 8192 + 262144) {
        int u = t - 8192;
        int n = u >> 9, k = u & 511;
        ws[W1T_OFF + u] = (__bf16)W1[k * 512 + n];
    } else if (t < PREP_TOTAL) {
        int u = t - (8192 + 262144);
        int n = u >> 9, k = u & 511;
        ws[W2T_OFF + u] = (n < 136) ? (__bf16)W2[k * 136 + n] : (__bf16)0.0f;
    }
}

__device__ __forceinline__ float fast_tanh(float x) {
#if __has_builtin(__builtin_amdgcn_exp2f)
    float e = __builtin_amdgcn_exp2f(x * 2.885390081777926f);
#else
    float e = exp2f(x * 2.885390081777926f);
#endif
    return 1.0f - 2.0f * __builtin_amdgcn_rcpf(e + 1.0f);
}

// h LDS: [64][512] bf16, 16B k-blocks XOR-swizzled by (m&7).
__device__ __forceinline__ int h_idx(int m, int k) {
    return m * 512 + ((((k >> 3) ^ (m & 7)) << 3)) + (k & 7);
}

// 32x32x16_bf16 fragment maps (C/D verified m74/m101; A/B K-contig):
//   A/B: m|n = lane&31, k = (lane>>5)*8 + j
//   C/D: col = lane&31, row = (reg&3) + 8*(reg>>2) + 4*(lane>>5)
//
// Register economics (R2-R7 lesson): a cap below natural demand -> 100-240 MB
// scratch spill -> ~400 us floor. (512,2) = cap 256; acc 64 AGPR + 2-stage
// pipeline operands (~64) + base (~40) stays far below cap -> 0 spill.
__global__ __launch_bounds__(512, 2)
void fused_mlp_quad(const float* __restrict__ points,
                    const float* __restrict__ b0,
                    const float* __restrict__ b1,
                    const float* __restrict__ b2,
                    const __bf16* __restrict__ ws,
                    float* __restrict__ out) {
    __shared__ __align__(16) unsigned char lds_raw[65536];
    __bf16* h  = (__bf16*)lds_raw;   // [64][512] swizzled bf16 (h0, then h1 in place)
    float* net = (float*)lds_raw;    // [64][137] fp32 overlay after phase 2

    const __bf16* w0t = ws + W0T_OFF;
    const __bf16* w1t = ws + W1T_OFF;
    const __bf16* w2t = ws + W2T_OFF;

    const int tid = threadIdx.x;
    const int w   = tid >> 6;     // wave 0..7
    const int l   = tid & 63;
    const int ln  = l & 31;       // 32x32 lane index
    const int hi  = l >> 5;       // k-half
    const int row0 = blockIdx.x * 64;

    const int ncb = w * 64;       // wave owns cols [ncb, ncb+64) for BOTH m-tiles

    // ---------- phase 0: h0 = tanh(x @ W0 + b0), K=16 = one MFMA step ----------
    {
        bf16x8 a[2];
#pragma unroll
        for (int mt = 0; mt < 2; ++mt) {
            const float* src = points + (row0 + mt * 32 + ln) * 16 + hi * 8;
            float4 p0 = ((const float4*)src)[0];
            float4 p1 = ((const float4*)src)[1];
            bf16x8 t;
            t[0] = (__bf16)p0.x; t[1] = (__bf16)p0.y; t[2] = (__bf16)p0.z; t[3] = (__bf16)p0.w;
            t[4] = (__bf16)p1.x; t[5] = (__bf16)p1.y; t[6] = (__bf16)p1.z; t[7] = (__bf16)p1.w;
            a[mt] = t;
        }
#pragma unroll
        for (int nt = 0; nt < 2; ++nt) {
            const int n = ncb + nt * 32 + ln;
            bf16x8 b = *(const bf16x8*)(w0t + n * 16 + hi * 8);
            float bias = b0[n];
#pragma unroll
            for (int mt = 0; mt < 2; ++mt) {
                f32x16 acc = {};
                acc = __builtin_amdgcn_mfma_f32_32x32x16_bf16(a[mt], b, acc, 0, 0, 0);
#pragma unroll
                for (int r = 0; r < 16; ++r) {
                    int m = mt * 32 + (r & 3) + 8 * (r >> 2) + 4 * hi;
                    h[h_idx(m, n)] = (__bf16)fast_tanh(acc[r] + bias);
                }
            }
        }
    }
    __syncthreads();

    // ---------- phase 1: h1 = tanh(h0 @ W1 + b1) ----------
    // wave tile 64x64 = 2 mt x 2 nt; acc = 64 AGPR. 2-stage pipeline:
    // issue iter kk+1's loads before iter kk's MFMAs (hides L2 ~250 cyc).
    f32x16 acc1[2][2] = {};
    {
        const __bf16* arow0 = h + ln * 512;          // m-tile 0
        const __bf16* arow1 = h + (32 + ln) * 512;   // m-tile 1; (32+ln)&7 == ln&7
        const int asw = ln & 7;
        const __bf16* bcol0 = w1t + (ncb + ln) * 512 + hi * 8;
        const __bf16* bcol1 = w1t + (ncb + 32 + ln) * 512 + hi * 8;

        bf16x8 a0, a1, bv0, bv1;
        {
            const int koff = ((hi ^ asw) << 3);
            a0  = *(const bf16x8*)(arow0 + koff);
            a1  = *(const bf16x8*)(arow1 + koff);
            bv0 = *(const bf16x8*)(bcol0);
            bv1 = *(const bf16x8*)(bcol1);
        }
#pragma unroll 2
        for (int kk = 0; kk < 32; ++kk) {
            bf16x8 na0, na1, nb0, nb1;
            if (kk + 1 < 32) {
                const int koff = (((((kk + 1) << 1) + hi) ^ asw) << 3);
                na0 = *(const bf16x8*)(arow0 + koff);
                na1 = *(const bf16x8*)(arow1 + koff);
                nb0 = *(const bf16x8*)(bcol0 + (kk + 1) * 16);
                nb1 = *(const bf16x8*)(bcol1 + (kk + 1) * 16);
            }
            acc1[0][0] = __builtin_amdgcn_mfma_f32_32x32x16_bf16(a0, bv0, acc1[0][0], 0, 0, 0);
            acc1[1][0] = __builtin_amdgcn_mfma_f32_32x32x16_bf16(a1, bv0, acc1[1][0], 0, 0, 0);
            acc1[0][1] = __builtin_amdgcn_mfma_f32_32x32x16_bf16(a0, bv1, acc1[0][1], 0, 0, 0);
            acc1[1][1] = __builtin_amdgcn_mfma_f32_32x32x16_bf16(a1, bv1, acc1[1][1], 0, 0, 0);
            a0 = na0; a1 = na1; bv0 = nb0; bv1 = nb1;
        }
    }
    __syncthreads();   // all h0 reads done; overwrite in place
#pragma unroll
    for (int nt = 0; nt < 2; ++nt) {
        const int n = ncb + nt * 32 + ln;
        float bias = b1[n];
#pragma unroll
        for (int mt = 0; mt < 2; ++mt) {
#pragma unroll
            for (int r = 0; r < 16; ++r) {
                int m = mt * 32 + (r & 3) + 8 * (r >> 2) + 4 * hi;
                h[h_idx(m, n)] = (__bf16)fast_tanh(acc1[mt][nt][r] + bias);
            }
        }
    }
    __syncthreads();

    // ---------- phase 2: net = h1 @ W2 + b2  (N padded 160 -> 5 nt x 2 mt) ----------
    // tile T: mt2 = T&1, nt2 = T>>1; T=w for all waves, plus T=8,9 on waves 0,1
    f32x16 acc2a = {}, acc2b = {};
    const int mt2 = w & 1;
    const int nt2 = w >> 1;
    {
        const __bf16* arow = h + (mt2 * 32 + ln) * 512;
        const int asw = ln & 7;
        const bool two = (w < 2);
        const __bf16* bcolA = w2t + (nt2 * 32 + ln) * 512 + hi * 8;
        const __bf16* bcolB = w2t + (128 + ln) * 512 + hi * 8;

        bf16x8 a, bA, bB;
        {
            const int koff = ((hi ^ asw) << 3);
            a  = *(const bf16x8*)(arow + koff);
            bA = *(const bf16x8*)(bcolA);
            bB = *(const bf16x8*)(bcolB);   // harmless over-read for w>=2
        }
#pragma unroll 2
        for (int kk = 0; kk < 32; ++kk) {
            bf16x8 na, nbA, nbB;
            if (kk + 1 < 32) {
                const int koff = (((((kk + 1) << 1) + hi) ^ asw) << 3);
                na  = *(const bf16x8*)(arow + koff);
                nbA = *(const bf16x8*)(bcolA + (kk + 1) * 16);
                if (two) nbB = *(const bf16x8*)(bcolB + (kk + 1) * 16);
            }
            acc2a = __builtin_amdgcn_mfma_f32_32x32x16_bf16(a, bA, acc2a, 0, 0, 0);
            if (two)
                acc2b = __builtin_amdgcn_mfma_f32_32x32x16_bf16(a, bB, acc2b, 0, 0, 0);
            a = na; bA = nbA; bB = nbB;
        }
    }
    __syncthreads();   // all h1 reads done; overwrite with net (fp32)
    {
        const int n = nt2 * 32 + ln;
        float bias = b2[n];   // nt2<=3 -> n<=127 < 136 always
#pragma unroll
        for (int r = 0; r < 16; ++r) {
            int m = mt2 * 32 + (r & 3) + 8 * (r >> 2) + 4 * hi;
            net[m * 137 + n] = acc2a[r] + bias;
        }
        if (w < 2) {
            const int n2 = 128 + ln;
            if (n2 < 136) {
                float bias2 = b2[n2];
#pragma unroll
                for (int r = 0; r < 16; ++r) {
                    int m = mt2 * 32 + (r & 3) + 8 * (r >> 2) + 4 * hi;
                    net[m * 137 + n2] = acc2b[r] + bias2;
                }
            }
        }
    }
    __syncthreads();

    // ---------- phase 3: vals = ||M^T x||^2 + eps*||x||^2 ----------
    // 8 threads per row x 64 rows = 512 threads, single pass
    {
        const int r  = tid >> 3;
        const int jg = tid & 7;
        const float* xp = points + (row0 + r) * 16;
        float xv[16];
#pragma unroll
        for (int i = 0; i < 4; ++i) {
            float4 v = ((const float4*)xp)[i];
            xv[i * 4 + 0] = v.x; xv[i * 4 + 1] = v.y;
            xv[i * 4 + 2] = v.z; xv[i * 4 + 3] = v.w;
        }
        float sumsq = 0.f;
#pragma unroll
        for (int i = 0; i < 16; ++i) sumsq += xv[i] * xv[i];
        float p = 0.f;
#pragma unroll
        for (int jj = 0; jj < 2; ++jj) {
            const int j = jg + jj * 8;
            float y = 0.f;
#pragma unroll
            for (int i = 0; i < 16; ++i) {
                float mv = net[r * 137 + ((i * (i + 1)) >> 1) + j];
                y += (i >= j) ? mv * xv[i] : 0.f;
            }
            p += y * y;
        }
        p += __shfl_xor(p, 1);
        p += __shfl_xor(p, 2);
        p += __shfl_xor(p, 4);
        if (jg == 0) out[row0 + r] = p + 1e-6f * sumsq;
    }
}

extern "C" void kernel_launch(void* const* d_in, const int* in_sizes, int n_in,
                              void* d_out, int out_size, void* d_ws, size_t ws_size,
                              hipStream_t stream) {
    const float* points = (const float*)d_in[0];
    const float* W0 = (const float*)d_in[1];
    const float* b0 = (const float*)d_in[2];
    const float* W1 = (const float*)d_in[3];
    const float* b1 = (const float*)d_in[4];
    const float* W2 = (const float*)d_in[5];
    const float* b2 = (const float*)d_in[6];
    __bf16* ws = (__bf16*)d_ws;
    float* out = (float*)d_out;

    prep_weights<<<(PREP_TOTAL + 255) / 256, 256, 0, stream>>>(W0, W1, W2, ws);

    const int B = in_sizes[0] / 16;   // 131072
    fused_mlp_quad<<<B / 64, 512, 0, stream>>>(points, b0, b1, b2, ws, out);
}

// Round 9
// 264.461 us; speedup vs baseline: 1.6859x; 1.2173x over previous
//
#include <hip/hip_runtime.h>

typedef __bf16 bf16x8 __attribute__((ext_vector_type(8)));
typedef float f32x16 __attribute__((ext_vector_type(16)));

// ---- workspace layout (bf16 element offsets), FRAGMENT-ORDERED weights ----
// A wave's b-frag for (n-tile, k-block) is 64 lanes x 16 B = 1 KB CONTIGUOUS:
//   elem (lane, j) at ((nt*NKBLK + kk)*64 + lane)*8 + j
//   encodes n = nt*32 + (lane&31), k = kk*16 + (lane>>5)*8 + j
#define W0F_OFF 0                 // 16 nt x 1 kk  x 64 x 8  = 8192
#define W1F_OFF 8192              // 16 nt x 32 kk x 64 x 8  = 262144
#define W2F_OFF (8192 + 262144)   // 5 nt  x 32 kk x 64 x 8  = 81920 (n>=136 zero)
#define PREP_TOTAL (8192 + 262144 + 81920)

__global__ void prep_weights(const float* __restrict__ W0,
                             const float* __restrict__ W1,
                             const float* __restrict__ W2,
                             __bf16* __restrict__ ws) {
    int t = blockIdx.x * 256 + threadIdx.x;
    if (t < 8192) {
        int j = t & 7, lane = (t >> 3) & 63, nt = t >> 9;
        int n = nt * 32 + (lane & 31);
        int k = (lane >> 5) * 8 + j;              // < 16
        ws[W0F_OFF + t] = (__bf16)W0[k * 512 + n];
    } else if (t < 8192 + 262144) {
        int u = t - 8192;
        int j = u & 7, lane = (u >> 3) & 63;
        int x = u >> 9;                            // nt*32 + kk
        int kk = x & 31, nt = x >> 5;
        int n = nt * 32 + (lane & 31);
        int k = kk * 16 + (lane >> 5) * 8 + j;
        ws[W1F_OFF + u] = (__bf16)W1[k * 512 + n];
    } else if (t < PREP_TOTAL) {
        int v = t - (8192 + 262144);
        int j = v & 7, lane = (v >> 3) & 63;
        int x = v >> 9;                            // nt*32 + kk
        int kk = x & 31, nt = x >> 5;
        int n = nt * 32 + (lane & 31);
        int k = kk * 16 + (lane >> 5) * 8 + j;
        ws[W2F_OFF + v] = (n < 136) ? (__bf16)W2[k * 136 + n] : (__bf16)0.0f;
    }
}

__device__ __forceinline__ float fast_tanh(float x) {
#if __has_builtin(__builtin_amdgcn_exp2f)
    float e = __builtin_amdgcn_exp2f(x * 2.885390081777926f);
#else
    float e = exp2f(x * 2.885390081777926f);
#endif
    return 1.0f - 2.0f * __builtin_amdgcn_rcpf(e + 1.0f);
}

// h LDS: [64][512] bf16, 16B k-blocks XOR-swizzled by (m&7).
__device__ __forceinline__ int h_idx(int m, int k) {
    return m * 512 + ((((k >> 3) ^ (m & 7)) << 3)) + (k & 7);
}

// 32x32x16_bf16 fragment maps (C/D verified m74/m101; A/B K-contig):
//   A/B: m|n = lane&31, k = (lane>>5)*8 + j
//   C/D: col = lane&31, row = (reg&3) + 8*(reg>>2) + 4*(lane>>5)
// Register economics (R2-R7): cap below natural demand -> 100-240 MB scratch
// spill -> ~400us floor. (512,2) = cap 256, natural ~85 -> 0 spill.
// R9: weights in fragment order -> b-load = 1KB contiguous burst (was a
// 32-line gather at 1KB lane stride; TCP line-rate was the R7/R8 limiter).
__global__ __launch_bounds__(512, 2)
void fused_mlp_quad(const float* __restrict__ points,
                    const float* __restrict__ b0,
                    const float* __restrict__ b1,
                    const float* __restrict__ b2,
                    const __bf16* __restrict__ ws,
                    float* __restrict__ out) {
    __shared__ __align__(16) unsigned char lds_raw[65536];
    __bf16* h  = (__bf16*)lds_raw;   // [64][512] swizzled bf16 (h0, then h1 in place)
    float* net = (float*)lds_raw;    // [64][137] fp32 overlay after phase 2

    const __bf16* w0f = ws + W0F_OFF;
    const __bf16* w1f = ws + W1F_OFF;
    const __bf16* w2f = ws + W2F_OFF;

    const int tid = threadIdx.x;
    const int w   = tid >> 6;     // wave 0..7
    const int l   = tid & 63;
    const int ln  = l & 31;       // 32x32 lane index
    const int hi  = l >> 5;       // k-half
    const int row0 = blockIdx.x * 64;

    const int ncb = w * 64;       // wave owns cols [ncb, ncb+64) for BOTH m-tiles
    const int lofs = l * 8;       // lane offset within a 1KB fragment record

    // ---------- phase 0: h0 = tanh(x @ W0 + b0), K=16 = one MFMA step ----------
    {
        bf16x8 a[2];
#pragma unroll
        for (int mt = 0; mt < 2; ++mt) {
            const float* src = points + (row0 + mt * 32 + ln) * 16 + hi * 8;
            float4 p0 = ((const float4*)src)[0];
            float4 p1 = ((const float4*)src)[1];
            bf16x8 t;
            t[0] = (__bf16)p0.x; t[1] = (__bf16)p0.y; t[2] = (__bf16)p0.z; t[3] = (__bf16)p0.w;
            t[4] = (__bf16)p1.x; t[5] = (__bf16)p1.y; t[6] = (__bf16)p1.z; t[7] = (__bf16)p1.w;
            a[mt] = t;
        }
#pragma unroll
        for (int nt = 0; nt < 2; ++nt) {
            const int ntg = w * 2 + nt;
            bf16x8 b = *(const bf16x8*)(w0f + ntg * 512 + lofs);
            const int n = ntg * 32 + ln;
            float bias = b0[n];
#pragma unroll
            for (int mt = 0; mt < 2; ++mt) {
                f32x16 acc = {};
                acc = __builtin_amdgcn_mfma_f32_32x32x16_bf16(a[mt], b, acc, 0, 0, 0);
#pragma unroll
                for (int r = 0; r < 16; ++r) {
                    int m = mt * 32 + (r & 3) + 8 * (r >> 2) + 4 * hi;
                    h[h_idx(m, n)] = (__bf16)fast_tanh(acc[r] + bias);
                }
            }
        }
    }
    __syncthreads();

    // ---------- phase 1: h1 = tanh(h0 @ W1 + b1) ----------
    // wave tile 64x64 = 2 mt x 2 nt; acc = 64 AGPR; b-loads = 1KB bursts
    f32x16 acc1[2][2] = {};
    {
        const __bf16* arow0 = h + ln * 512;          // m-tile 0
        const __bf16* arow1 = h + (32 + ln) * 512;   // m-tile 1; (32+ln)&7 == ln&7
        const int asw = ln & 7;
        // tile ntg = w*2+nt: records at w1f + (ntg*32 + kk)*512 + lofs
        const __bf16* bt0 = w1f + ((w * 2 + 0) * 32) * 512 + lofs;
        const __bf16* bt1 = w1f + ((w * 2 + 1) * 32) * 512 + lofs;
        for (int kk = 0; kk < 32; ++kk) {
            const int koff = ((((kk << 1) + hi) ^ asw) << 3);
            bf16x8 a0 = *(const bf16x8*)(arow0 + koff);
            bf16x8 a1 = *(const bf16x8*)(arow1 + koff);
            bf16x8 bv0 = *(const bf16x8*)(bt0 + kk * 512);
            bf16x8 bv1 = *(const bf16x8*)(bt1 + kk * 512);
            acc1[0][0] = __builtin_amdgcn_mfma_f32_32x32x16_bf16(a0, bv0, acc1[0][0], 0, 0, 0);
            acc1[1][0] = __builtin_amdgcn_mfma_f32_32x32x16_bf16(a1, bv0, acc1[1][0], 0, 0, 0);
            acc1[0][1] = __builtin_amdgcn_mfma_f32_32x32x16_bf16(a0, bv1, acc1[0][1], 0, 0, 0);
            acc1[1][1] = __builtin_amdgcn_mfma_f32_32x32x16_bf16(a1, bv1, acc1[1][1], 0, 0, 0);
        }
    }
    __syncthreads();   // all h0 reads done; overwrite in place
#pragma unroll
    for (int nt = 0; nt < 2; ++nt) {
        const int n = ncb + nt * 32 + ln;
        float bias = b1[n];
#pragma unroll
        for (int mt = 0; mt < 2; ++mt) {
#pragma unroll
            for (int r = 0; r < 16; ++r) {
                int m = mt * 32 + (r & 3) + 8 * (r >> 2) + 4 * hi;
                h[h_idx(m, n)] = (__bf16)fast_tanh(acc1[mt][nt][r] + bias);
            }
        }
    }
    __syncthreads();

    // ---------- phase 2: net = h1 @ W2 + b2  (N padded 160 -> 5 nt x 2 mt) ----------
    // tile T: mt2 = T&1, nt2 = T>>1; T=w for all waves, plus T=8,9 on waves 0,1
    f32x16 acc2a = {}, acc2b = {};
    const int mt2 = w & 1;
    const int nt2 = w >> 1;
    {
        const __bf16* arow = h + (mt2 * 32 + ln) * 512;
        const int asw = ln & 7;
        const bool two = (w < 2);
        const __bf16* btA = w2f + (nt2 * 32) * 512 + lofs;
        const __bf16* btB = w2f + (4 * 32) * 512 + lofs;
        for (int kk = 0; kk < 32; ++kk) {
            bf16x8 a = *(const bf16x8*)(arow + ((((kk << 1) + hi) ^ asw) << 3));
            bf16x8 bA = *(const bf16x8*)(btA + kk * 512);
            acc2a = __builtin_amdgcn_mfma_f32_32x32x16_bf16(a, bA, acc2a, 0, 0, 0);
            if (two) {
                bf16x8 bB = *(const bf16x8*)(btB + kk * 512);
                acc2b = __builtin_amdgcn_mfma_f32_32x32x16_bf16(a, bB, acc2b, 0, 0, 0);
            }
        }
    }
    __syncthreads();   // all h1 reads done; overwrite with net (fp32)
    {
        const int n = nt2 * 32 + ln;
        float bias = b2[n];   // nt2<=3 -> n<=127 < 136 always
#pragma unroll
        for (int r = 0; r < 16; ++r) {
            int m = mt2 * 32 + (r & 3) + 8 * (r >> 2) + 4 * hi;
            net[m * 137 + n] = acc2a[r] + bias;
        }
        if (w < 2) {
            const int n2 = 128 + ln;
            if (n2 < 136) {
                float bias2 = b2[n2];
#pragma unroll
                for (int r = 0; r < 16; ++r) {
                    int m = mt2 * 32 + (r & 3) + 8 * (r >> 2) + 4 * hi;
                    net[m * 137 + n2] = acc2b[r] + bias2;
                }
            }
        }
    }
    __syncthreads();

    // ---------- phase 3: vals = ||M^T x||^2 + eps*||x||^2 ----------
    // 8 threads per row x 64 rows = 512 threads, single pass
    {
        const int r  = tid >> 3;
        const int jg = tid & 7;
        const float* xp = points + (row0 + r) * 16;
        float xv[16];
#pragma unroll
        for (int i = 0; i < 4; ++i) {
            float4 v = ((const float4*)xp)[i];
            xv[i * 4 + 0] = v.x; xv[i * 4 + 1] = v.y;
            xv[i * 4 + 2] = v.z; xv[i * 4 + 3] = v.w;
        }
        float sumsq = 0.f;
#pragma unroll
        for (int i = 0; i < 16; ++i) sumsq += xv[i] * xv[i];
        float p = 0.f;
#pragma unroll
        for (int jj = 0; jj < 2; ++jj) {
            const int j = jg + jj * 8;
            float y = 0.f;
#pragma unroll
            for (int i = 0; i < 16; ++i) {
                float mv = net[r * 137 + ((i * (i + 1)) >> 1) + j];
                y += (i >= j) ? mv * xv[i] : 0.f;
            }
            p += y * y;
        }
        p += __shfl_xor(p, 1);
        p += __shfl_xor(p, 2);
        p += __shfl_xor(p, 4);
        if (jg == 0) out[row0 + r] = p + 1e-6f * sumsq;
    }
}

extern "C" void kernel_launch(void* const* d_in, const int* in_sizes, int n_in,
                              void* d_out, int out_size, void* d_ws, size_t ws_size,
                              hipStream_t stream) {
    const float* points = (const float*)d_in[0];
    const float* W0 = (const float*)d_in[1];
    const float* b0 = (const float*)d_in[2];
    const float* W1 = (const float*)d_in[3];
    const float* b1 = (const float*)d_in[4];
    const float* W2 = (const float*)d_in[5];
    const float* b2 = (const float*)d_in[6];
    __bf16* ws = (__bf16*)d_ws;
    float* out = (float*)d_out;

    prep_weights<<<(PREP_TOTAL + 255) / 256, 256, 0, stream>>>(W0, W1, W2, ws);

    const int B = in_sizes[0] / 16;   // 131072
    fused_mlp_quad<<<B / 64, 512, 0, stream>>>(points, b0, b1, b2, ws, out);
}

// Round 10
// 261.068 us; speedup vs baseline: 1.7078x; 1.0130x over previous
//
#include <hip/hip_runtime.h>

typedef __bf16 bf16x8 __attribute__((ext_vector_type(8)));
typedef float f32x16 __attribute__((ext_vector_type(16)));

// ---- workspace layout (bf16 element offsets), FRAGMENT-ORDERED weights ----
// A wave's b-frag for (n-tile, k-block) is 64 lanes x 16 B = 1 KB CONTIGUOUS:
//   elem (lane, j) at ((nt*NKBLK + kk)*64 + lane)*8 + j
//   encodes n = nt*32 + (lane&31), k = kk*16 + (lane>>5)*8 + j
#define W0F_OFF 0                 // 16 nt x 1 kk  x 64 x 8  = 8192
#define W1F_OFF 8192              // 16 nt x 32 kk x 64 x 8  = 262144
#define W2F_OFF (8192 + 262144)   // 5 nt  x 32 kk x 64 x 8  = 81920 (n>=136 zero)
#define PREP_TOTAL (8192 + 262144 + 81920)

__global__ void prep_weights(const float* __restrict__ W0,
                             const float* __restrict__ W1,
                             const float* __restrict__ W2,
                             __bf16* __restrict__ ws) {
    int t = blockIdx.x * 256 + threadIdx.x;
    if (t < 8192) {
        int j = t & 7, lane = (t >> 3) & 63, nt = t >> 9;
        int n = nt * 32 + (lane & 31);
        int k = (lane >> 5) * 8 + j;              // < 16
        ws[W0F_OFF + t] = (__bf16)W0[k * 512 + n];
    } else if (t < 8192 + 262144) {
        int u = t - 8192;
        int j = u & 7, lane = (u >> 3) & 63;
        int x = u >> 9;                            // nt*32 + kk
        int kk = x & 31, nt = x >> 5;
        int n = nt * 32 + (lane & 31);
        int k = kk * 16 + (lane >> 5) * 8 + j;
        ws[W1F_OFF + u] = (__bf16)W1[k * 512 + n];
    } else if (t < PREP_TOTAL) {
        int v = t - (8192 + 262144);
        int j = v & 7, lane = (v >> 3) & 63;
        int x = v >> 9;                            // nt*32 + kk
        int kk = x & 31, nt = x >> 5;
        int n = nt * 32 + (lane & 31);
        int k = kk * 16 + (lane >> 5) * 8 + j;
        ws[W2F_OFF + v] = (n < 136) ? (__bf16)W2[k * 136 + n] : (__bf16)0.0f;
    }
}

__device__ __forceinline__ float fast_tanh(float x) {
#if __has_builtin(__builtin_amdgcn_exp2f)
    float e = __builtin_amdgcn_exp2f(x * 2.885390081777926f);
#else
    float e = exp2f(x * 2.885390081777926f);
#endif
    return 1.0f - 2.0f * __builtin_amdgcn_rcpf(e + 1.0f);
}

// h LDS: [32][512] bf16, 16B k-blocks XOR-swizzled by (m&7).
__device__ __forceinline__ int h_idx(int m, int k) {
    return m * 512 + ((((k >> 3) ^ (m & 7)) << 3)) + (k & 7);
}

// 32x32x16_bf16 fragment maps (C/D verified m74/m101; A/B K-contig):
//   A/B: m|n = lane&31, k = (lane>>5)*8 + j
//   C/D: col = lane&31, row = (reg&3) + 8*(reg>>2) + 4*(lane>>5)
//
// R10 structure: 256 thr (4 waves), BM=32, LDS 32KB. Per-wave footprint
// ~ arch 90-100 + 64 AGPR acc = ~160 of the 512/SIMD pool -> 2-3 blocks
// co-resident per CU; independent blocks at different phases overlap
// tanh-VALU/barrier-drain with MFMA K-loops (R7-R9 had 1 block/CU: phases
// strictly serial -> MfmaUtil 17.7 + VALUBusy 24.7, 58% dead).
// (256,2) cap=256 total regs: no spill possible (R2-R6 lesson).
__global__ __launch_bounds__(256, 2)
void fused_mlp_quad(const float* __restrict__ points,
                    const float* __restrict__ b0,
                    const float* __restrict__ b1,
                    const float* __restrict__ b2,
                    const __bf16* __restrict__ ws,
                    float* __restrict__ out) {
    __shared__ __align__(16) unsigned char lds_raw[32768];
    __bf16* h  = (__bf16*)lds_raw;   // [32][512] swizzled bf16 (h0, then h1 in place)
    float* net = (float*)lds_raw;    // [32][137] fp32 overlay after phase 2 (17.5KB)

    const __bf16* w0f = ws + W0F_OFF;
    const __bf16* w1f = ws + W1F_OFF;
    const __bf16* w2f = ws + W2F_OFF;

    const int tid = threadIdx.x;
    const int w   = tid >> 6;     // wave 0..3
    const int l   = tid & 63;
    const int ln  = l & 31;       // 32x32 lane index
    const int hi  = l >> 5;       // k-half
    const int row0 = blockIdx.x * 32;

    const int lofs = l * 8;       // lane offset within a 1KB fragment record

    // ---------- phase 0: h0 = tanh(x @ W0 + b0), K=16 = one MFMA step ----------
    {
        const float* src = points + (row0 + ln) * 16 + hi * 8;
        float4 p0 = ((const float4*)src)[0];
        float4 p1 = ((const float4*)src)[1];
        bf16x8 a;
        a[0] = (__bf16)p0.x; a[1] = (__bf16)p0.y; a[2] = (__bf16)p0.z; a[3] = (__bf16)p0.w;
        a[4] = (__bf16)p1.x; a[5] = (__bf16)p1.y; a[6] = (__bf16)p1.z; a[7] = (__bf16)p1.w;
#pragma unroll
        for (int t = 0; t < 4; ++t) {
            const int ntg = w * 4 + t;
            bf16x8 b = *(const bf16x8*)(w0f + ntg * 512 + lofs);
            const int n = ntg * 32 + ln;
            float bias = b0[n];
            f32x16 acc = {};
            acc = __builtin_amdgcn_mfma_f32_32x32x16_bf16(a, b, acc, 0, 0, 0);
#pragma unroll
            for (int r = 0; r < 16; ++r) {
                int m = (r & 3) + 8 * (r >> 2) + 4 * hi;
                h[h_idx(m, n)] = (__bf16)fast_tanh(acc[r] + bias);
            }
        }
    }
    __syncthreads();

    // ---------- phase 1: h1 = tanh(h0 @ W1 + b1) ----------
    // wave tile: 32 rows x 128 cols = 4 n-tiles (nt = w*4+t); acc = 64 AGPR
    f32x16 acc1[4] = {};
    {
        const __bf16* arow = h + ln * 512;
        const int asw = ln & 7;
        const __bf16* bt[4];
#pragma unroll
        for (int t = 0; t < 4; ++t)
            bt[t] = w1f + ((w * 4 + t) * 32) * 512 + lofs;
        for (int kk = 0; kk < 32; ++kk) {
            const int koff = ((((kk << 1) + hi) ^ asw) << 3);
            bf16x8 a = *(const bf16x8*)(arow + koff);
#pragma unroll
            for (int t = 0; t < 4; ++t) {
                bf16x8 b = *(const bf16x8*)(bt[t] + kk * 512);
                acc1[t] = __builtin_amdgcn_mfma_f32_32x32x16_bf16(a, b, acc1[t], 0, 0, 0);
            }
        }
    }
    __syncthreads();   // all h0 reads done; overwrite in place
#pragma unroll
    for (int t = 0; t < 4; ++t) {
        const int n = (w * 4 + t) * 32 + ln;
        float bias = b1[n];
#pragma unroll
        for (int r = 0; r < 16; ++r) {
            int m = (r & 3) + 8 * (r >> 2) + 4 * hi;
            h[h_idx(m, n)] = (__bf16)fast_tanh(acc1[t][r] + bias);
        }
    }
    __syncthreads();

    // ---------- phase 2: net = h1 @ W2 + b2  (N padded 160 -> 5 n-tiles) ----------
    // nt = w on all waves; wave 0 additionally nt = 4 (cols 128..159)
    f32x16 acc2a = {}, acc2b = {};
    {
        const __bf16* arow = h + ln * 512;
        const int asw = ln & 7;
        const bool two = (w == 0);
        const __bf16* btA = w2f + (w * 32) * 512 + lofs;
        const __bf16* btB = w2f + (4 * 32) * 512 + lofs;
        for (int kk = 0; kk < 32; ++kk) {
            bf16x8 a = *(const bf16x8*)(arow + ((((kk << 1) + hi) ^ asw) << 3));
            bf16x8 bA = *(const bf16x8*)(btA + kk * 512);
            acc2a = __builtin_amdgcn_mfma_f32_32x32x16_bf16(a, bA, acc2a, 0, 0, 0);
            if (two) {
                bf16x8 bB = *(const bf16x8*)(btB + kk * 512);
                acc2b = __builtin_amdgcn_mfma_f32_32x32x16_bf16(a, bB, acc2b, 0, 0, 0);
            }
        }
    }
    __syncthreads();   // all h1 reads done; overwrite with net (fp32)
    {
        const int n = w * 32 + ln;   // <= 127 < 136 always
        float bias = b2[n];
#pragma unroll
        for (int r = 0; r < 16; ++r) {
            int m = (r & 3) + 8 * (r >> 2) + 4 * hi;
            net[m * 137 + n] = acc2a[r] + bias;
        }
        if (w == 0) {
            const int n2 = 128 + ln;
            if (n2 < 136) {
                float bias2 = b2[n2];
#pragma unroll
                for (int r = 0; r < 16; ++r) {
                    int m = (r & 3) + 8 * (r >> 2) + 4 * hi;
                    net[m * 137 + n2] = acc2b[r] + bias2;
                }
            }
        }
    }
    __syncthreads();

    // ---------- phase 3: vals = ||M^T x||^2 + eps*||x||^2 ----------
    // 8 threads per row x 32 rows = 256 threads, single pass
    {
        const int r  = tid >> 3;
        const int jg = tid & 7;
        const float* xp = points + (row0 + r) * 16;
        float xv[16];
#pragma unroll
        for (int i = 0; i < 4; ++i) {
            float4 v = ((const float4*)xp)[i];
            xv[i * 4 + 0] = v.x; xv[i * 4 + 1] = v.y;
            xv[i * 4 + 2] = v.z; xv[i * 4 + 3] = v.w;
        }
        float sumsq = 0.f;
#pragma unroll
        for (int i = 0; i < 16; ++i) sumsq += xv[i] * xv[i];
        float p = 0.f;
#pragma unroll
        for (int jj = 0; jj < 2; ++jj) {
            const int j = jg + jj * 8;
            float y = 0.f;
#pragma unroll
            for (int i = 0; i < 16; ++i) {
                float mv = net[r * 137 + ((i * (i + 1)) >> 1) + j];
                y += (i >= j) ? mv * xv[i] : 0.f;
            }
            p += y * y;
        }
        p += __shfl_xor(p, 1);
        p += __shfl_xor(p, 2);
        p += __shfl_xor(p, 4);
        if (jg == 0) out[row0 + r] = p + 1e-6f * sumsq;
    }
}

extern "C" void kernel_launch(void* const* d_in, const int* in_sizes, int n_in,
                              void* d_out, int out_size, void* d_ws, size_t ws_size,
                              hipStream_t stream) {
    const float* points = (const float*)d_in[0];
    const float* W0 = (const float*)d_in[1];
    const float* b0 = (const float*)d_in[2];
    const float* W1 = (const float*)d_in[3];
    const float* b1 = (const float*)d_in[4];
    const float* W2 = (const float*)d_in[5];
    const float* b2 = (const float*)d_in[6];
    __bf16* ws = (__bf16*)d_ws;
    float* out = (float*)d_out;

    prep_weights<<<(PREP_TOTAL + 255) / 256, 256, 0, stream>>>(W0, W1, W2, ws);

    const int B = in_sizes[0] / 16;   // 131072
    fused_mlp_quad<<<B / 32, 256, 0, stream>>>(points, b0, b1, b2, ws, out);
}

// Round 11
// 224.609 us; speedup vs baseline: 1.9851x; 1.1623x over previous
//
#include <hip/hip_runtime.h>

typedef __bf16 bf16x8 __attribute__((ext_vector_type(8)));
typedef float f32x16 __attribute__((ext_vector_type(16)));

// ---- workspace layout (bf16 element offsets), FRAGMENT-ORDERED weights ----
// A wave's b-frag for (n-tile, k-block) is 64 lanes x 16 B = 1 KB CONTIGUOUS:
//   elem (lane, j) at ((nt*NKBLK + kk)*64 + lane)*8 + j
//   encodes n = nt*32 + (lane&31), k = kk*16 + (lane>>5)*8 + j
#define W0F_OFF 0                 // 16 nt x 1 kk  x 64 x 8  = 8192
#define W1F_OFF 8192              // 16 nt x 32 kk x 64 x 8  = 262144
#define W2F_OFF (8192 + 262144)   // 5 nt  x 32 kk x 64 x 8  = 81920 (n>=136 zero)
#define PREP_TOTAL (8192 + 262144 + 81920)

__global__ void prep_weights(const float* __restrict__ W0,
                             const float* __restrict__ W1,
                             const float* __restrict__ W2,
                             __bf16* __restrict__ ws) {
    int t = blockIdx.x * 256 + threadIdx.x;
    if (t < 8192) {
        int j = t & 7, lane = (t >> 3) & 63, nt = t >> 9;
        int n = nt * 32 + (lane & 31);
        int k = (lane >> 5) * 8 + j;              // < 16
        ws[W0F_OFF + t] = (__bf16)W0[k * 512 + n];
    } else if (t < 8192 + 262144) {
        int u = t - 8192;
        int j = u & 7, lane = (u >> 3) & 63;
        int x = u >> 9;                            // nt*32 + kk
        int kk = x & 31, nt = x >> 5;
        int n = nt * 32 + (lane & 31);
        int k = kk * 16 + (lane >> 5) * 8 + j;
        ws[W1F_OFF + u] = (__bf16)W1[k * 512 + n];
    } else if (t < PREP_TOTAL) {
        int v = t - (8192 + 262144);
        int j = v & 7, lane = (v >> 3) & 63;
        int x = v >> 9;                            // nt*32 + kk
        int kk = x & 31, nt = x >> 5;
        int n = nt * 32 + (lane & 31);
        int k = kk * 16 + (lane >> 5) * 8 + j;
        ws[W2F_OFF + v] = (n < 136) ? (__bf16)W2[k * 136 + n] : (__bf16)0.0f;
    }
}

__device__ __forceinline__ float fast_tanh(float x) {
#if __has_builtin(__builtin_amdgcn_exp2f)
    float e = __builtin_amdgcn_exp2f(x * 2.885390081777926f);
#else
    float e = exp2f(x * 2.885390081777926f);
#endif
    return 1.0f - 2.0f * __builtin_amdgcn_rcpf(e + 1.0f);
}

// h LDS: [32][512] bf16, 16B k-blocks XOR-swizzled by (m&7).
__device__ __forceinline__ int h_idx(int m, int k) {
    return m * 512 + ((((k >> 3) ^ (m & 7)) << 3)) + (k & 7);
}

// 32x32x16_bf16 fragment maps (C/D verified m74/m101; A/B K-contig):
//   A/B: m|n = lane&31, k = (lane>>5)*8 + j
//   C/D: col = lane&31, row = (reg&3) + 8*(reg>>2) + 4*(lane>>5)
//
// R11: R10 structure (256 thr, BM=32, LDS 32KB) + two levers:
//  (a) super-iter-2 load batching: 8 b-frags + 2 a-frags issued together,
//      one L2 latency stall per 8 MFMAs (was per 4) — straight-line batch,
//      not a rotation, so the compiler cannot delete it (R8 lesson);
//  (b) register diet to cross the 3-waves/SIMD threshold: in-flight
//      acc 64 AGPR + b 64 + a 16 + addr ~15 = ~159 <= 168 -> 12 waves/CU.
// (256,2) cap=256: no forced-cap spill possible (R2-R6 lesson).
__global__ __launch_bounds__(256, 2)
void fused_mlp_quad(const float* __restrict__ points,
                    const float* __restrict__ b0,
                    const float* __restrict__ b1,
                    const float* __restrict__ b2,
                    const __bf16* __restrict__ ws,
                    float* __restrict__ out) {
    __shared__ __align__(16) unsigned char lds_raw[32768];
    __bf16* h  = (__bf16*)lds_raw;   // [32][512] swizzled bf16 (h0, then h1 in place)
    float* net = (float*)lds_raw;    // [32][137] fp32 overlay after phase 2 (17.5KB)

    const __bf16* w0f = ws + W0F_OFF;
    const __bf16* w1f = ws + W1F_OFF;
    const __bf16* w2f = ws + W2F_OFF;

    const int tid = threadIdx.x;
    const int w   = tid >> 6;     // wave 0..3
    const int l   = tid & 63;
    const int ln  = l & 31;       // 32x32 lane index
    const int hi  = l >> 5;       // k-half
    const int row0 = blockIdx.x * 32;

    const int lofs = l * 8;       // lane offset within a 1KB fragment record

    // ---------- phase 0: h0 = tanh(x @ W0 + b0), K=16 = one MFMA step ----------
    {
        const float* src = points + (row0 + ln) * 16 + hi * 8;
        float4 p0 = ((const float4*)src)[0];
        float4 p1 = ((const float4*)src)[1];
        bf16x8 a;
        a[0] = (__bf16)p0.x; a[1] = (__bf16)p0.y; a[2] = (__bf16)p0.z; a[3] = (__bf16)p0.w;
        a[4] = (__bf16)p1.x; a[5] = (__bf16)p1.y; a[6] = (__bf16)p1.z; a[7] = (__bf16)p1.w;
#pragma unroll
        for (int t = 0; t < 4; ++t) {
            const int ntg = w * 4 + t;
            bf16x8 b = *(const bf16x8*)(w0f + ntg * 512 + lofs);
            const int n = ntg * 32 + ln;
            float bias = b0[n];
            f32x16 acc = {};
            acc = __builtin_amdgcn_mfma_f32_32x32x16_bf16(a, b, acc, 0, 0, 0);
#pragma unroll
            for (int r = 0; r < 16; ++r) {
                int m = (r & 3) + 8 * (r >> 2) + 4 * hi;
                h[h_idx(m, n)] = (__bf16)fast_tanh(acc[r] + bias);
            }
        }
    }
    __syncthreads();

    // ---------- phase 1: h1 = tanh(h0 @ W1 + b1) ----------
    // wave tile: 32 rows x 128 cols = 4 n-tiles; acc = 64 AGPR.
    // Super-iter over 2 kk: batch 2 a-frags + 8 b-frags, then 8 MFMAs.
    f32x16 acc1[4] = {};
    {
        const __bf16* arow = h + ln * 512;
        const int asw = ln & 7;
        // wave-uniform b bases (SGPR), lane-varying voffset shared across nt
        const __bf16* w1b0 = w1f + (w * 4 + 0) * 16384;
        const __bf16* w1b1 = w1f + (w * 4 + 1) * 16384;
        const __bf16* w1b2 = w1f + (w * 4 + 2) * 16384;
        const __bf16* w1b3 = w1f + (w * 4 + 3) * 16384;
        for (int ks = 0; ks < 16; ++ks) {
            bf16x8 aa[2], bb[2][4];
#pragma unroll
            for (int u = 0; u < 2; ++u) {
                const int kk = ks * 2 + u;
                const int vo = kk * 512 + lofs;
                aa[u] = *(const bf16x8*)(arow + ((((kk << 1) + hi) ^ asw) << 3));
                bb[u][0] = *(const bf16x8*)(w1b0 + vo);
                bb[u][1] = *(const bf16x8*)(w1b1 + vo);
                bb[u][2] = *(const bf16x8*)(w1b2 + vo);
                bb[u][3] = *(const bf16x8*)(w1b3 + vo);
            }
#pragma unroll
            for (int u = 0; u < 2; ++u) {
                acc1[0] = __builtin_amdgcn_mfma_f32_32x32x16_bf16(aa[u], bb[u][0], acc1[0], 0, 0, 0);
                acc1[1] = __builtin_amdgcn_mfma_f32_32x32x16_bf16(aa[u], bb[u][1], acc1[1], 0, 0, 0);
                acc1[2] = __builtin_amdgcn_mfma_f32_32x32x16_bf16(aa[u], bb[u][2], acc1[2], 0, 0, 0);
                acc1[3] = __builtin_amdgcn_mfma_f32_32x32x16_bf16(aa[u], bb[u][3], acc1[3], 0, 0, 0);
            }
        }
    }
    __syncthreads();   // all h0 reads done; overwrite in place
#pragma unroll
    for (int t = 0; t < 4; ++t) {
        const int n = (w * 4 + t) * 32 + ln;
        float bias = b1[n];
#pragma unroll
        for (int r = 0; r < 16; ++r) {
            int m = (r & 3) + 8 * (r >> 2) + 4 * hi;
            h[h_idx(m, n)] = (__bf16)fast_tanh(acc1[t][r] + bias);
        }
    }
    __syncthreads();

    // ---------- phase 2: net = h1 @ W2 + b2  (N padded 160 -> 5 n-tiles) ----------
    // nt = w on all waves; wave 0 additionally nt = 4 (cols 128..159)
    f32x16 acc2a = {}, acc2b = {};
    {
        const __bf16* arow = h + ln * 512;
        const int asw = ln & 7;
        const bool two = (w == 0);
        const __bf16* w2bA = w2f + w * 16384;
        const __bf16* w2bB = w2f + 4 * 16384;
        for (int ks = 0; ks < 16; ++ks) {
            bf16x8 aa[2], bA[2], bB[2];
#pragma unroll
            for (int u = 0; u < 2; ++u) {
                const int kk = ks * 2 + u;
                const int vo = kk * 512 + lofs;
                aa[u] = *(const bf16x8*)(arow + ((((kk << 1) + hi) ^ asw) << 3));
                bA[u] = *(const bf16x8*)(w2bA + vo);
                if (two) bB[u] = *(const bf16x8*)(w2bB + vo);
            }
#pragma unroll
            for (int u = 0; u < 2; ++u) {
                acc2a = __builtin_amdgcn_mfma_f32_32x32x16_bf16(aa[u], bA[u], acc2a, 0, 0, 0);
                if (two)
                    acc2b = __builtin_amdgcn_mfma_f32_32x32x16_bf16(aa[u], bB[u], acc2b, 0, 0, 0);
            }
        }
    }
    __syncthreads();   // all h1 reads done; overwrite with net (fp32)
    {
        const int n = w * 32 + ln;   // <= 127 < 136 always
        float bias = b2[n];
#pragma unroll
        for (int r = 0; r < 16; ++r) {
            int m = (r & 3) + 8 * (r >> 2) + 4 * hi;
            net[m * 137 + n] = acc2a[r] + bias;
        }
        if (w == 0) {
            const int n2 = 128 + ln;
            if (n2 < 136) {
                float bias2 = b2[n2];
#pragma unroll
                for (int r = 0; r < 16; ++r) {
                    int m = (r & 3) + 8 * (r >> 2) + 4 * hi;
                    net[m * 137 + n2] = acc2b[r] + bias2;
                }
            }
        }
    }
    __syncthreads();

    // ---------- phase 3: vals = ||M^T x||^2 + eps*||x||^2 ----------
    // 8 threads per row x 32 rows = 256 threads, single pass
    {
        const int r  = tid >> 3;
        const int jg = tid & 7;
        const float* xp = points + (row0 + r) * 16;
        float xv[16];
#pragma unroll
        for (int i = 0; i < 4; ++i) {
            float4 v = ((const float4*)xp)[i];
            xv[i * 4 + 0] = v.x; xv[i * 4 + 1] = v.y;
            xv[i * 4 + 2] = v.z; xv[i * 4 + 3] = v.w;
        }
        float sumsq = 0.f;
#pragma unroll
        for (int i = 0; i < 16; ++i) sumsq += xv[i] * xv[i];
        float p = 0.f;
#pragma unroll
        for (int jj = 0; jj < 2; ++jj) {
            const int j = jg + jj * 8;
            float y = 0.f;
#pragma unroll
            for (int i = 0; i < 16; ++i) {
                float mv = net[r * 137 + ((i * (i + 1)) >> 1) + j];
                y += (i >= j) ? mv * xv[i] : 0.f;
            }
            p += y * y;
        }
        p += __shfl_xor(p, 1);
        p += __shfl_xor(p, 2);
        p += __shfl_xor(p, 4);
        if (jg == 0) out[row0 + r] = p + 1e-6f * sumsq;
    }
}

extern "C" void kernel_launch(void* const* d_in, const int* in_sizes, int n_in,
                              void* d_out, int out_size, void* d_ws, size_t ws_size,
                              hipStream_t stream) {
    const float* points = (const float*)d_in[0];
    const float* W0 = (const float*)d_in[1];
    const float* b0 = (const float*)d_in[2];
    const float* W1 = (const float*)d_in[3];
    const float* b1 = (const float*)d_in[4];
    const float* W2 = (const float*)d_in[5];
    const float* b2 = (const float*)d_in[6];
    __bf16* ws = (__bf16*)d_ws;
    float* out = (float*)d_out;

    prep_weights<<<(PREP_TOTAL + 255) / 256, 256, 0, stream>>>(W0, W1, W2, ws);

    const int B = in_sizes[0] / 16;   // 131072
    fused_mlp_quad<<<B / 32, 256, 0, stream>>>(points, b0, b1, b2, ws, out);
}

// Round 12
// 222.341 us; speedup vs baseline: 2.0053x; 1.0102x over previous
//
#include <hip/hip_runtime.h>

typedef __bf16 bf16x4 __attribute__((ext_vector_type(4)));
typedef __bf16 bf16x8 __attribute__((ext_vector_type(8)));
typedef float f32x16 __attribute__((ext_vector_type(16)));

// ---- workspace layout (bf16 element offsets), FRAGMENT-ORDERED weights ----
// A wave's weight frag for (n-tile, k-block) is 64 lanes x 16 B = 1 KB contig:
//   elem (lane, j) at ((nt*NKBLK + kk)*64 + lane)*8 + j
//   encodes n = nt*32 + (lane&31), k = kk*16 + (lane>>5)*8 + j
#define W0F_OFF 0                 // 16 nt x 1 kk  x 64 x 8  = 8192
#define W1F_OFF 8192              // 16 nt x 32 kk x 64 x 8  = 262144
#define W2F_OFF (8192 + 262144)   // 5 nt  x 32 kk x 64 x 8  = 81920 (n>=136 zero)
#define PREP_TOTAL (8192 + 262144 + 81920)

__global__ void prep_weights(const float* __restrict__ W0,
                             const float* __restrict__ W1,
                             const float* __restrict__ W2,
                             __bf16* __restrict__ ws) {
    int t = blockIdx.x * 256 + threadIdx.x;
    if (t < 8192) {
        int j = t & 7, lane = (t >> 3) & 63, nt = t >> 9;
        int n = nt * 32 + (lane & 31);
        int k = (lane >> 5) * 8 + j;              // < 16
        ws[W0F_OFF + t] = (__bf16)W0[k * 512 + n];
    } else if (t < 8192 + 262144) {
        int u = t - 8192;
        int j = u & 7, lane = (u >> 3) & 63;
        int x = u >> 9;                            // nt*32 + kk
        int kk = x & 31, nt = x >> 5;
        int n = nt * 32 + (lane & 31);
        int k = kk * 16 + (lane >> 5) * 8 + j;
        ws[W1F_OFF + u] = (__bf16)W1[k * 512 + n];
    } else if (t < PREP_TOTAL) {
        int v = t - (8192 + 262144);
        int j = v & 7, lane = (v >> 3) & 63;
        int x = v >> 9;                            // nt*32 + kk
        int kk = x & 31, nt = x >> 5;
        int n = nt * 32 + (lane & 31);
        int k = kk * 16 + (lane >> 5) * 8 + j;
        ws[W2F_OFF + v] = (n < 136) ? (__bf16)W2[k * 136 + n] : (__bf16)0.0f;
    }
}

__device__ __forceinline__ float fast_tanh(float x) {
#if __has_builtin(__builtin_amdgcn_exp2f)
    float e = __builtin_amdgcn_exp2f(x * 2.885390081777926f);
#else
    float e = exp2f(x * 2.885390081777926f);
#endif
    return 1.0f - 2.0f * __builtin_amdgcn_rcpf(e + 1.0f);
}

// h LDS: [32][520] bf16 (pad 512->520: rows 1040 B = 16B-aligned, bank shift
// 4/row). NO XOR swizzle -> K-loop a-reads are ds_read_b128 with immediate
// offsets (zero per-iter VALU). Writes are packed b64 (4-way bank alias, ok).
#define HSTR 520
// net LDS: [32][140] f32 overlay (stride 140 = mult of 4 -> float4 writes).
#define NSTR 140

// R12: MFMA operand swap. D = mfma(W_frag, act_frag): weight n_out lands in
// REGS, batch row in LANES -> D is directly in the next layer's B-operand
// (activation) orientation. Epilogues write 4 consecutive n_out as one packed
// b64/b128 (was 64 scalar b16 + XOR addr math = the 40% VALUBusy of R11).
// Fragment maps (m74/m101 C/D; A/B same lane map as before):
//   W(A): n_out = lane&31, k = (lane>>5)*8 + j
//   act(B): batch = lane&31, k = (lane>>5)*8 + j
//   D: batch = lane&31, n_out = (reg&3) + 8*(reg>>2) + 4*(lane>>5)
// (256,2) cap=256: no forced-cap spill (R2-R6 lesson).
__global__ __launch_bounds__(256, 2)
void fused_mlp_quad(const float* __restrict__ points,
                    const float* __restrict__ b0,
                    const float* __restrict__ b1,
                    const float* __restrict__ b2,
                    const __bf16* __restrict__ ws,
                    float* __restrict__ out) {
    __shared__ __align__(16) unsigned char lds_raw[33280];
    __bf16* h  = (__bf16*)lds_raw;   // [32][HSTR] bf16 (h0, then h1 in place)
    float* net = (float*)lds_raw;    // [32][NSTR] f32 overlay after phase 2

    const __bf16* w0f = ws + W0F_OFF;
    const __bf16* w1f = ws + W1F_OFF;
    const __bf16* w2f = ws + W2F_OFF;

    const int tid = threadIdx.x;
    const int w   = tid >> 6;     // wave 0..3
    const int l   = tid & 63;
    const int ln  = l & 31;       // batch row within tile / 32x32 lane index
    const int hi  = l >> 5;       // k-half
    const int row0 = blockIdx.x * 32;

    const int lofs = l * 8;       // lane offset within a 1KB fragment record

    // ---------- phase 0: h0 = tanh(x @ W0 + b0), K=16 = one MFMA step ----------
    {
        // act(B) frag: x[row0+ln][hi*8 .. +7]
        const float* src = points + (row0 + ln) * 16 + hi * 8;
        float4 p0 = ((const float4*)src)[0];
        float4 p1 = ((const float4*)src)[1];
        bf16x8 bx;
        bx[0] = (__bf16)p0.x; bx[1] = (__bf16)p0.y; bx[2] = (__bf16)p0.z; bx[3] = (__bf16)p0.w;
        bx[4] = (__bf16)p1.x; bx[5] = (__bf16)p1.y; bx[6] = (__bf16)p1.z; bx[7] = (__bf16)p1.w;
#pragma unroll
        for (int t = 0; t < 4; ++t) {
            const int ntg = w * 4 + t;
            bf16x8 wf = *(const bf16x8*)(w0f + ntg * 512 + lofs);
            f32x16 acc = {};
            acc = __builtin_amdgcn_mfma_f32_32x32x16_bf16(wf, bx, acc, 0, 0, 0);
#pragma unroll
            for (int rg = 0; rg < 4; ++rg) {
                const int n0 = ntg * 32 + 8 * rg + 4 * hi;
                float4 bias = *(const float4*)(b0 + n0);
                bf16x4 v;
                v[0] = (__bf16)fast_tanh(acc[4 * rg + 0] + bias.x);
                v[1] = (__bf16)fast_tanh(acc[4 * rg + 1] + bias.y);
                v[2] = (__bf16)fast_tanh(acc[4 * rg + 2] + bias.z);
                v[3] = (__bf16)fast_tanh(acc[4 * rg + 3] + bias.w);
                *(bf16x4*)(h + ln * HSTR + n0) = v;
            }
        }
    }
    __syncthreads();

    // ---------- phase 1: h1 = tanh(h0 @ W1 + b1) ----------
    // wave: 4 n-tiles (w*4+t); acc = 64 AGPR. Super-iter 2 kk: batch
    // 2 act-frags + 8 weight-frags, then 8 MFMAs (one L2 stall per 8 MFMAs).
    f32x16 acc1[4] = {};
    {
        const __bf16* arow = h + ln * HSTR + hi * 8;   // + kk*16 (imm offsets)
        const __bf16* w1b0 = w1f + (w * 4 + 0) * 16384 + lofs;
        const __bf16* w1b1 = w1f + (w * 4 + 1) * 16384 + lofs;
        const __bf16* w1b2 = w1f + (w * 4 + 2) * 16384 + lofs;
        const __bf16* w1b3 = w1f + (w * 4 + 3) * 16384 + lofs;
        for (int ks = 0; ks < 16; ++ks) {
            bf16x8 aa[2], bb[2][4];
#pragma unroll
            for (int u = 0; u < 2; ++u) {
                const int kk = ks * 2 + u;
                const int vo = kk * 512;
                aa[u] = *(const bf16x8*)(arow + kk * 16);
                bb[u][0] = *(const bf16x8*)(w1b0 + vo);
                bb[u][1] = *(const bf16x8*)(w1b1 + vo);
                bb[u][2] = *(const bf16x8*)(w1b2 + vo);
                bb[u][3] = *(const bf16x8*)(w1b3 + vo);
            }
#pragma unroll
            for (int u = 0; u < 2; ++u) {
                acc1[0] = __builtin_amdgcn_mfma_f32_32x32x16_bf16(bb[u][0], aa[u], acc1[0], 0, 0, 0);
                acc1[1] = __builtin_amdgcn_mfma_f32_32x32x16_bf16(bb[u][1], aa[u], acc1[1], 0, 0, 0);
                acc1[2] = __builtin_amdgcn_mfma_f32_32x32x16_bf16(bb[u][2], aa[u], acc1[2], 0, 0, 0);
                acc1[3] = __builtin_amdgcn_mfma_f32_32x32x16_bf16(bb[u][3], aa[u], acc1[3], 0, 0, 0);
            }
        }
    }
    __syncthreads();   // all h0 reads done; overwrite in place
#pragma unroll
    for (int t = 0; t < 4; ++t) {
#pragma unroll
        for (int rg = 0; rg < 4; ++rg) {
            const int n0 = (w * 4 + t) * 32 + 8 * rg + 4 * hi;
            float4 bias = *(const float4*)(b1 + n0);
            bf16x4 v;
            v[0] = (__bf16)fast_tanh(acc1[t][4 * rg + 0] + bias.x);
            v[1] = (__bf16)fast_tanh(acc1[t][4 * rg + 1] + bias.y);
            v[2] = (__bf16)fast_tanh(acc1[t][4 * rg + 2] + bias.z);
            v[3] = (__bf16)fast_tanh(acc1[t][4 * rg + 3] + bias.w);
            *(bf16x4*)(h + ln * HSTR + n0) = v;
        }
    }
    __syncthreads();

    // ---------- phase 2: net = h1 @ W2 + b2  (N padded 160 -> 5 n-tiles) ----------
    // nt = w on all waves; wave 0 additionally nt = 4 (cols 128..159)
    f32x16 acc2a = {}, acc2b = {};
    {
        const __bf16* arow = h + ln * HSTR + hi * 8;
        const bool two = (w == 0);
        const __bf16* w2bA = w2f + w * 16384 + lofs;
        const __bf16* w2bB = w2f + 4 * 16384 + lofs;
        for (int ks = 0; ks < 16; ++ks) {
            bf16x8 aa[2], bA[2], bB[2];
#pragma unroll
            for (int u = 0; u < 2; ++u) {
                const int kk = ks * 2 + u;
                const int vo = kk * 512;
                aa[u] = *(const bf16x8*)(arow + kk * 16);
                bA[u] = *(const bf16x8*)(w2bA + vo);
                if (two) bB[u] = *(const bf16x8*)(w2bB + vo);
            }
#pragma unroll
            for (int u = 0; u < 2; ++u) {
                acc2a = __builtin_amdgcn_mfma_f32_32x32x16_bf16(bA[u], aa[u], acc2a, 0, 0, 0);
                if (two)
                    acc2b = __builtin_amdgcn_mfma_f32_32x32x16_bf16(bB[u], aa[u], acc2b, 0, 0, 0);
            }
        }
    }
    __syncthreads();   // all h1 reads done; overwrite with net (fp32)
    {
#pragma unroll
        for (int rg = 0; rg < 4; ++rg) {
            const int n0 = w * 32 + 8 * rg + 4 * hi;   // <= 124, +3 <= 127 < 136
            float4 bias = *(const float4*)(b2 + n0);
            float4 v;
            v.x = acc2a[4 * rg + 0] + bias.x;
            v.y = acc2a[4 * rg + 1] + bias.y;
            v.z = acc2a[4 * rg + 2] + bias.z;
            v.w = acc2a[4 * rg + 3] + bias.w;
            *(float4*)(net + ln * NSTR + n0) = v;
        }
        if (w == 0) {
            // extra tile nt=4: only rg==0 has n0+3 < 136 (n0 = 128 or 132)
            const int n0 = 128 + 4 * hi;
            float4 bias = *(const float4*)(b2 + n0);
            float4 v;
            v.x = acc2b[0] + bias.x;
            v.y = acc2b[1] + bias.y;
            v.z = acc2b[2] + bias.z;
            v.w = acc2b[3] + bias.w;
            *(float4*)(net + ln * NSTR + n0) = v;
        }
    }
    __syncthreads();

    // ---------- phase 3: vals = ||M^T x||^2 + eps*||x||^2 ----------
    // 8 threads per row x 32 rows = 256 threads, single pass
    {
        const int r  = tid >> 3;
        const int jg = tid & 7;
        const float* xp = points + (row0 + r) * 16;
        float xv[16];
#pragma unroll
        for (int i = 0; i < 4; ++i) {
            float4 v = ((const float4*)xp)[i];
            xv[i * 4 + 0] = v.x; xv[i * 4 + 1] = v.y;
            xv[i * 4 + 2] = v.z; xv[i * 4 + 3] = v.w;
        }
        float sumsq = 0.f;
#pragma unroll
        for (int i = 0; i < 16; ++i) sumsq += xv[i] * xv[i];
        float p = 0.f;
#pragma unroll
        for (int jj = 0; jj < 2; ++jj) {
            const int j = jg + jj * 8;
            float y = 0.f;
#pragma unroll
            for (int i = 0; i < 16; ++i) {
                float mv = net[r * NSTR + ((i * (i + 1)) >> 1) + j];
                y += (i >= j) ? mv * xv[i] : 0.f;
            }
            p += y * y;
        }
        p += __shfl_xor(p, 1);
        p += __shfl_xor(p, 2);
        p += __shfl_xor(p, 4);
        if (jg == 0) out[row0 + r] = p + 1e-6f * sumsq;
    }
}

extern "C" void kernel_launch(void* const* d_in, const int* in_sizes, int n_in,
                              void* d_out, int out_size, void* d_ws, size_t ws_size,
                              hipStream_t stream) {
    const float* points = (const float*)d_in[0];
    const float* W0 = (const float*)d_in[1];
    const float* b0 = (const float*)d_in[2];
    const float* W1 = (const float*)d_in[3];
    const float* b1 = (const float*)d_in[4];
    const float* W2 = (const float*)d_in[5];
    const float* b2 = (const float*)d_in[6];
    __bf16* ws = (__bf16*)d_ws;
    float* out = (float*)d_out;

    prep_weights<<<(PREP_TOTAL + 255) / 256, 256, 0, stream>>>(W0, W1, W2, ws);

    const int B = in_sizes[0] / 16;   // 131072
    fused_mlp_quad<<<B / 32, 256, 0, stream>>>(points, b0, b1, b2, ws, out);
}